// Round 1
// baseline (477.259 us; speedup 1.0000x reference)
//
#include <hip/hip_runtime.h>
#include <hip/hip_bf16.h>
#include <cstdint>
#include <cstddef>

typedef float  f32x4 __attribute__((ext_vector_type(4)));
typedef _Float16 f16x8 __attribute__((ext_vector_type(8)));

#define DEVFN __device__ __forceinline__

// ---------------------------------------------------------------------------
// Cubic B-spline basis, exact replica of the reference recursion (f32).
// G=5, K=3: knots t[j] = (j-3)*0.4 - 1.0, j=0..11; output 8 basis values.
// ---------------------------------------------------------------------------
DEVFN void bspline8(float x, float bv[8]) {
    float t[12];
#pragma unroll
    for (int j = 0; j < 12; ++j) t[j] = (float)(j - 3) * 0.4f - 1.0f;
    float B[11];
#pragma unroll
    for (int j = 0; j < 11; ++j) B[j] = (x >= t[j] && x < t[j + 1]) ? 1.0f : 0.0f;
#pragma unroll
    for (int p = 1; p <= 3; ++p) {
#pragma unroll
        for (int j = 0; j + p < 11; ++j) {
            float left  = (x - t[j]) / (t[j + p] - t[j]);
            float right = (t[j + p + 1] - x) / (t[j + p + 1] - t[j + 1]);
            B[j] = left * B[j] + right * B[j + 1];
        }
    }
#pragma unroll
    for (int g = 0; g < 8; ++g) bv[g] = B[g];
}

// ---------------------------------------------------------------------------
// prep_a: X (Nrows x D, f32) -> Aaug (Nrows x 9*D, fp16), k = c*D + i
//   c=0: silu(x);  c=1+g: B_g(x)
// one thread per input element; all 9 stores are lane-coalesced.
// ---------------------------------------------------------------------------
__global__ void prep_a_kernel(const float* __restrict__ X,
                              _Float16* __restrict__ Aaug,
                              int total, int dshift) {
    int idx = blockIdx.x * 256 + threadIdx.x;
    if (idx >= total) return;
    const int D = 1 << dshift;
    const int K = 9 << dshift;
    const int n = idx >> dshift;
    const int i = idx & (D - 1);
    float x = X[idx];
    float s = x / (1.0f + expf(-x));   // silu
    float bv[8];
    bspline8(x, bv);
    _Float16* dst = Aaug + (size_t)n * K + i;
    dst[0] = (_Float16)s;
#pragma unroll
    for (int g = 0; g < 8; ++g) dst[(size_t)(g + 1) * D] = (_Float16)bv[g];
}

// ---------------------------------------------------------------------------
// prep_w: coef (Din x Dout x 8), scale_base/scale_sp (Din x Dout)
//   -> WT (Dout x 9*Din, fp16), WT[o][c*Din + i]:
//      c=0: scale_base[i][o]; c=1+g: coef[i][o][g]*scale_sp[i][o]
// thread idx: i = idx & (Din-1) (lane-fast) -> coalesced WT stores.
// ---------------------------------------------------------------------------
__global__ void prep_w_kernel(const float* __restrict__ coef,
                              const float* __restrict__ sb,
                              const float* __restrict__ sp,
                              _Float16* __restrict__ WT,
                              int total, int din_shift, int dout) {
    int idx = blockIdx.x * 256 + threadIdx.x;
    if (idx >= total) return;
    const int Din = 1 << din_shift;
    const int i = idx & (Din - 1);
    const int o = idx >> din_shift;
    const size_t K = (size_t)9 << din_shift;
    const size_t cidx = (size_t)i * dout + o;
    float base  = sb[cidx];
    float scale = sp[cidx];
    const float* cp = coef + cidx * 8;
    _Float16* dst = WT + (size_t)o * K + i;
    dst[0] = (_Float16)base;
#pragma unroll
    for (int g = 0; g < 8; ++g) dst[(size_t)(g + 1) * Din] = (_Float16)(cp[g] * scale);
}

// ---------------------------------------------------------------------------
// GEMM: C (MxN, f32) = A (MxK fp16, row-major) * WT (NxK fp16, row-major)^T
// m97 structure: global_load_lds width 16, single LDS buffer, 2 barriers/K.
// 256 threads = 4 waves in 2x2; 16x16x32 f16 MFMA.
// ---------------------------------------------------------------------------
DEVFN void gload16(const void* g, void* l) {
    __builtin_amdgcn_global_load_lds(
        (const __attribute__((address_space(1))) void*)g,
        (__attribute__((address_space(3))) void*)l, 16, 0, 0);
}

template <int BM, int BN>
__global__ __launch_bounds__(256) void gemm_f16_bt(
    const _Float16* __restrict__ A,
    const _Float16* __restrict__ WT,
    float* __restrict__ C,
    int K, int N) {
    constexpr int BK = 64;
    constexpr int FM = BM / 32;   // frags per wave (M)
    constexpr int FN = BN / 32;   // frags per wave (N)
    __shared__ _Float16 Alds[BM * BK];
    __shared__ _Float16 Blds[BN * BK];

    const int tid  = threadIdx.x;
    const int lane = tid & 63;
    const int w    = tid >> 6;
    const int wm   = w >> 1;
    const int wn   = w & 1;
    const size_t bm = (size_t)blockIdx.y * BM;
    const size_t bn = (size_t)blockIdx.x * BN;

    constexpr int A_ISS = (BM * BK) / 2048;  // 2048 halfs staged per issue
    constexpr int B_ISS = (BN * BK) / 2048;

    const f32x4 vzero = {0.0f, 0.0f, 0.0f, 0.0f};
    f32x4 acc[FM][FN];
#pragma unroll
    for (int m = 0; m < FM; ++m)
#pragma unroll
        for (int n = 0; n < FN; ++n) acc[m][n] = vzero;

    const int arow = tid >> 3;          // tid*8 / 64
    const int acol = (tid & 7) * 8;

    for (int k0 = 0; k0 < K; k0 += BK) {
#pragma unroll
        for (int is = 0; is < A_ISS; ++is) {
            const _Float16* gp = A + (bm + (size_t)(arow + is * 32)) * K + k0 + acol;
            gload16(gp, Alds + is * 2048 + w * 512);
        }
#pragma unroll
        for (int is = 0; is < B_ISS; ++is) {
            const _Float16* gp = WT + (bn + (size_t)(arow + is * 32)) * K + k0 + acol;
            gload16(gp, Blds + is * 2048 + w * 512);
        }
        __syncthreads();

#pragma unroll
        for (int ks = 0; ks < BK; ks += 32) {
            f16x8 af[FM], bf[FN];
#pragma unroll
            for (int m = 0; m < FM; ++m)
                af[m] = *(const f16x8*)(Alds + (wm * FM * 16 + m * 16 + (lane & 15)) * BK
                                        + ks + (lane >> 4) * 8);
#pragma unroll
            for (int n = 0; n < FN; ++n)
                bf[n] = *(const f16x8*)(Blds + (wn * FN * 16 + n * 16 + (lane & 15)) * BK
                                        + ks + (lane >> 4) * 8);
#pragma unroll
            for (int m = 0; m < FM; ++m)
#pragma unroll
                for (int n = 0; n < FN; ++n)
                    acc[m][n] = __builtin_amdgcn_mfma_f32_16x16x32_f16(
                        af[m], bf[n], acc[m][n], 0, 0, 0);
        }
        __syncthreads();
    }

    // epilogue: C/D layout col = lane&15, row = (lane>>4)*4 + reg  [m89]
    const int r0 = wm * FM * 16 + (lane >> 4) * 4;
    const int c0 = wn * FN * 16 + (lane & 15);
#pragma unroll
    for (int m = 0; m < FM; ++m)
#pragma unroll
        for (int n = 0; n < FN; ++n)
#pragma unroll
            for (int r = 0; r < 4; ++r)
                C[(bm + r0 + m * 16 + r) * (size_t)N + bn + c0 + n * 16] = acc[m][n][r];
}

// ---------------------------------------------------------------------------
// launch
// ---------------------------------------------------------------------------
extern "C" void kernel_launch(void* const* d_in, const int* in_sizes, int n_in,
                              void* d_out, int out_size, void* d_ws, size_t ws_size,
                              hipStream_t stream) {
    const float* x     = (const float*)d_in[0];
    const float* coef1 = (const float*)d_in[1];
    const float* sb1   = (const float*)d_in[2];
    const float* sp1   = (const float*)d_in[3];
    const float* coef2 = (const float*)d_in[4];
    const float* sb2   = (const float*)d_in[5];
    const float* sp2   = (const float*)d_in[6];
    float* out = (float*)d_out;

    const int M  = 4096;           // bsz*seq
    const int D1 = 512;            // d_model
    const int D2 = 1024;           // hidden
    const int K1 = 9 * D1;         // 4608
    const int K2 = 9 * D2;         // 9216

    char* ws = (char*)d_ws;
    float*    h    = (float*)ws;                                     // 16.78 MB
    _Float16* Aaug = (_Float16*)(ws + (size_t)M * D2 * 4);           // up to 75.5 MB
    _Float16* WT   = (_Float16*)(ws + (size_t)M * D2 * 4 + (size_t)M * K2 * 2); // 9.44 MB

    // ---- layer 1 ----
    prep_w_kernel<<<(D1 * D2) / 256, 256, 0, stream>>>(coef1, sb1, sp1, WT,
                                                       D1 * D2, 9, D2);
    prep_a_kernel<<<(M * D1) / 256, 256, 0, stream>>>(x, Aaug, M * D1, 9);
    {
        dim3 grid(D2 / 128, M / 64);
        gemm_f16_bt<64, 128><<<grid, 256, 0, stream>>>(Aaug, WT, h, K1, D2);
    }
    // ---- layer 2 ----
    prep_w_kernel<<<(D2 * D1) / 256, 256, 0, stream>>>(coef2, sb2, sp2, WT,
                                                       D1 * D2, 10, D1);
    prep_a_kernel<<<(M * D2) / 256, 256, 0, stream>>>(h, Aaug, M * D2, 10);
    {
        dim3 grid(D1 / 128, M / 64);
        gemm_f16_bt<64, 128><<<grid, 256, 0, stream>>>(Aaug, WT, out, K2, D1);
    }
}

// Round 2
// 388.595 us; speedup vs baseline: 1.2282x; 1.2282x over previous
//
#include <hip/hip_runtime.h>
#include <hip/hip_bf16.h>
#include <cstdint>
#include <cstddef>

typedef float  f32x4 __attribute__((ext_vector_type(4)));
typedef _Float16 f16x8 __attribute__((ext_vector_type(8)));

#define DEVFN __device__ __forceinline__

// ---------------------------------------------------------------------------
// Cubic B-spline basis, exact replica of the reference recursion (f32).
// ---------------------------------------------------------------------------
DEVFN void bspline8(float x, float bv[8]) {
    float t[12];
#pragma unroll
    for (int j = 0; j < 12; ++j) t[j] = (float)(j - 3) * 0.4f - 1.0f;
    float B[11];
#pragma unroll
    for (int j = 0; j < 11; ++j) B[j] = (x >= t[j] && x < t[j + 1]) ? 1.0f : 0.0f;
#pragma unroll
    for (int p = 1; p <= 3; ++p) {
#pragma unroll
        for (int j = 0; j + p < 11; ++j) {
            float left  = (x - t[j]) / (t[j + p] - t[j]);
            float right = (t[j + p + 1] - x) / (t[j + p + 1] - t[j + 1]);
            B[j] = left * B[j] + right * B[j + 1];
        }
    }
#pragma unroll
    for (int g = 0; g < 8; ++g) bv[g] = B[g];
}

// ---------------------------------------------------------------------------
// prep_a: X (Nrows x D, f32) -> Aaug (Nrows x 9*D, fp16), k = c*D + i
// ---------------------------------------------------------------------------
__global__ void prep_a_kernel(const float* __restrict__ X,
                              _Float16* __restrict__ Aaug,
                              int total, int dshift) {
    int idx = blockIdx.x * 256 + threadIdx.x;
    if (idx >= total) return;
    const int D = 1 << dshift;
    const int K = 9 << dshift;
    const int n = idx >> dshift;
    const int i = idx & (D - 1);
    float x = X[idx];
    float s = x / (1.0f + expf(-x));   // silu
    float bv[8];
    bspline8(x, bv);
    _Float16* dst = Aaug + (size_t)n * K + i;
    dst[0] = (_Float16)s;
#pragma unroll
    for (int g = 0; g < 8; ++g) dst[(size_t)(g + 1) * D] = (_Float16)bv[g];
}

// ---------------------------------------------------------------------------
// prep_w: coef (Din x Dout x 8), scale_base/scale_sp (Din x Dout)
//   -> WT (Dout x 9*Din, fp16)
// ---------------------------------------------------------------------------
__global__ void prep_w_kernel(const float* __restrict__ coef,
                              const float* __restrict__ sb,
                              const float* __restrict__ sp,
                              _Float16* __restrict__ WT,
                              int total, int din_shift, int dout) {
    int idx = blockIdx.x * 256 + threadIdx.x;
    if (idx >= total) return;
    const int Din = 1 << din_shift;
    const int i = idx & (Din - 1);
    const int o = idx >> din_shift;
    const size_t K = (size_t)9 << din_shift;
    const size_t cidx = (size_t)i * dout + o;
    float base  = sb[cidx];
    float scale = sp[cidx];
    const float* cp = coef + cidx * 8;
    _Float16* dst = WT + (size_t)o * K + i;
    dst[0] = (_Float16)base;
#pragma unroll
    for (int g = 0; g < 8; ++g) dst[(size_t)(g + 1) * Din] = (_Float16)(cp[g] * scale);
}

// ---------------------------------------------------------------------------
// GEMM 128x128 tile, BK=64, 4 waves (2x2), 4x4 16x16x32 f16 MFMA frags/wave.
// T2 XOR swizzle: LDS linear dest (global_load_lds), pre-swizzled GLOBAL
// source col-group (c8 ^= row&7), same XOR on ds_read addresses.
// Split-K over blockIdx.z, f32 atomic-add epilogue (C pre-zeroed).
// ---------------------------------------------------------------------------
DEVFN void gload16(const void* g, void* l) {
    __builtin_amdgcn_global_load_lds(
        (const __attribute__((address_space(1))) void*)g,
        (__attribute__((address_space(3))) void*)l, 16, 0, 0);
}

__global__ __launch_bounds__(256) void gemm128_f16_bt(
    const _Float16* __restrict__ A,
    const _Float16* __restrict__ WT,
    float* __restrict__ C,
    int K, int N, int klen) {
    constexpr int BK = 64;
    __shared__ _Float16 Alds[128 * BK];
    __shared__ _Float16 Blds[128 * BK];

    const int tid  = threadIdx.x;
    const int lane = tid & 63;
    const int w    = tid >> 6;
    const int wm   = w >> 1;
    const int wn   = w & 1;
    const size_t bm = (size_t)blockIdx.y * 128;
    const size_t bn = (size_t)blockIdx.x * 128;
    const int kbase = blockIdx.z * klen;

    const f32x4 vzero = {0.0f, 0.0f, 0.0f, 0.0f};
    f32x4 acc[4][4];
#pragma unroll
    for (int m = 0; m < 4; ++m)
#pragma unroll
        for (int n = 0; n < 4; ++n) acc[m][n] = vzero;

    // staging geometry: thread tid covers LDS row r = is*32 + (tid>>3),
    // col-group c8 = tid&7 (16B groups). Global source group is swizzled.
    const int srow = tid >> 3;
    const int c8   = tid & 7;

    for (int k0 = kbase; k0 < kbase + klen; k0 += BK) {
#pragma unroll
        for (int is = 0; is < 4; ++is) {
            const int r  = is * 32 + srow;
            const int sg = (c8 ^ (r & 7)) << 3;  // swizzled source col (elems)
            gload16(A + (bm + r) * (size_t)K + k0 + sg,
                    Alds + is * 2048 + w * 512);
            gload16(WT + (bn + r) * (size_t)K + k0 + sg,
                    Blds + is * 2048 + w * 512);
        }
        __syncthreads();

#pragma unroll
        for (int ks = 0; ks < BK; ks += 32) {
            f16x8 af[4], bf[4];
            const int g = (ks >> 3) + (lane >> 4);      // k col-group 0..7
#pragma unroll
            for (int m = 0; m < 4; ++m) {
                const int row = wm * 64 + m * 16 + (lane & 15);
                af[m] = *(const f16x8*)(Alds + row * BK + ((g ^ (row & 7)) << 3));
            }
#pragma unroll
            for (int n = 0; n < 4; ++n) {
                const int row = wn * 64 + n * 16 + (lane & 15);
                bf[n] = *(const f16x8*)(Blds + row * BK + ((g ^ (row & 7)) << 3));
            }
#pragma unroll
            for (int m = 0; m < 4; ++m)
#pragma unroll
                for (int n = 0; n < 4; ++n)
                    acc[m][n] = __builtin_amdgcn_mfma_f32_16x16x32_f16(
                        af[m], bf[n], acc[m][n], 0, 0, 0);
        }
        __syncthreads();
    }

    // epilogue: C/D layout col = lane&15, row = (lane>>4)*4 + reg  [m89]
    const int r0 = wm * 64 + (lane >> 4) * 4;
    const int c0 = wn * 64 + (lane & 15);
#pragma unroll
    for (int m = 0; m < 4; ++m)
#pragma unroll
        for (int n = 0; n < 4; ++n)
#pragma unroll
            for (int r = 0; r < 4; ++r)
                unsafeAtomicAdd(&C[(bm + r0 + m * 16 + r) * (size_t)N + bn + c0 + n * 16],
                                acc[m][n][r]);
}

// ---------------------------------------------------------------------------
// launch
// ---------------------------------------------------------------------------
extern "C" void kernel_launch(void* const* d_in, const int* in_sizes, int n_in,
                              void* d_out, int out_size, void* d_ws, size_t ws_size,
                              hipStream_t stream) {
    const float* x     = (const float*)d_in[0];
    const float* coef1 = (const float*)d_in[1];
    const float* sb1   = (const float*)d_in[2];
    const float* sp1   = (const float*)d_in[3];
    const float* coef2 = (const float*)d_in[4];
    const float* sb2   = (const float*)d_in[5];
    const float* sp2   = (const float*)d_in[6];
    float* out = (float*)d_out;

    const int M  = 4096;           // bsz*seq
    const int D1 = 512;            // d_model
    const int D2 = 1024;           // hidden
    const int K1 = 9 * D1;         // 4608
    const int K2 = 9 * D2;         // 9216

    char* ws = (char*)d_ws;
    float*    h    = (float*)ws;                                     // 16.78 MB
    _Float16* Aaug = (_Float16*)(ws + (size_t)M * D2 * 4);           // up to 75.5 MB
    _Float16* WT   = (_Float16*)(ws + (size_t)M * D2 * 4 + (size_t)M * K2 * 2); // 9.44 MB

    hipMemsetAsync(h, 0, (size_t)M * D2 * 4, stream);
    hipMemsetAsync(out, 0, (size_t)M * D1 * 4, stream);

    // ---- layer 1 ----
    prep_w_kernel<<<(D1 * D2) / 256, 256, 0, stream>>>(coef1, sb1, sp1, WT,
                                                       D1 * D2, 9, D2);
    prep_a_kernel<<<(M * D1) / 256, 256, 0, stream>>>(x, Aaug, M * D1, 9);
    {
        dim3 grid(D2 / 128, M / 128, 2);   // split-K x2 -> 512 blocks
        gemm128_f16_bt<<<grid, 256, 0, stream>>>(Aaug, WT, h, K1, D2, K1 / 2);
    }
    // ---- layer 2 ----
    prep_w_kernel<<<(D2 * D1) / 256, 256, 0, stream>>>(coef2, sb2, sp2, WT,
                                                       D1 * D2, 10, D1);
    prep_a_kernel<<<(M * D2) / 256, 256, 0, stream>>>(h, Aaug, M * D2, 10);
    {
        dim3 grid(D1 / 128, M / 128, 4);   // split-K x4 -> 512 blocks
        gemm128_f16_bt<<<grid, 256, 0, stream>>>(Aaug, WT, out, K2, D1, K2 / 4);
    }
}

// Round 3
// 294.837 us; speedup vs baseline: 1.6187x; 1.3180x over previous
//
#include <hip/hip_runtime.h>
#include <hip/hip_bf16.h>
#include <cstdint>
#include <cstddef>

typedef float  f32x4 __attribute__((ext_vector_type(4)));
typedef _Float16 f16x8 __attribute__((ext_vector_type(8)));

#define DEVFN __device__ __forceinline__

// ---------------------------------------------------------------------------
// Cubic B-spline basis on the UNIFORM grid: all knot gaps are p*h (constants),
// so the reference's divisions become multiplies by 1/(p*h).
// t[j] = (j-3)*0.4 - 1.0, j=0..11; output 8 basis values.
// ---------------------------------------------------------------------------
DEVFN void bspline8(float x, float bv[8]) {
    float t[12];
#pragma unroll
    for (int j = 0; j < 12; ++j) t[j] = (float)(j - 3) * 0.4f - 1.0f;
    float B[11];
#pragma unroll
    for (int j = 0; j < 11; ++j) B[j] = (x >= t[j] && x < t[j + 1]) ? 1.0f : 0.0f;
    const float rp[3] = {2.5f, 1.25f, 0.8333333333f};  // 1/(p*0.4)
#pragma unroll
    for (int p = 1; p <= 3; ++p) {
#pragma unroll
        for (int j = 0; j + p < 11; ++j) {
            float left  = (x - t[j]) * rp[p - 1];
            float right = (t[j + p + 1] - x) * rp[p - 1];
            B[j] = left * B[j] + right * B[j + 1];
        }
    }
#pragma unroll
    for (int g = 0; g < 8; ++g) bv[g] = B[g];
}

// ---------------------------------------------------------------------------
// prep_a: X (Nrows x D, f32) -> Aaug (Nrows x 9*D, fp16), k = c*D + i
// ---------------------------------------------------------------------------
__global__ void prep_a_kernel(const float* __restrict__ X,
                              _Float16* __restrict__ Aaug,
                              int total, int dshift) {
    int idx = blockIdx.x * 256 + threadIdx.x;
    if (idx >= total) return;
    const int D = 1 << dshift;
    const int K = 9 << dshift;
    const int n = idx >> dshift;
    const int i = idx & (D - 1);
    float x = X[idx];
    float s = x * __builtin_amdgcn_rcpf(1.0f + __expf(-x));   // silu (fast)
    float bv[8];
    bspline8(x, bv);
    _Float16* dst = Aaug + (size_t)n * K + i;
    dst[0] = (_Float16)s;
#pragma unroll
    for (int g = 0; g < 8; ++g) dst[(size_t)(g + 1) * D] = (_Float16)bv[g];
}

// ---------------------------------------------------------------------------
// prep_w: coef (Din x Dout x 8), scale_base/scale_sp (Din x Dout)
//   -> WT (Dout x 9*Din, fp16)
// ---------------------------------------------------------------------------
__global__ void prep_w_kernel(const float* __restrict__ coef,
                              const float* __restrict__ sb,
                              const float* __restrict__ sp,
                              _Float16* __restrict__ WT,
                              int total, int din_shift, int dout) {
    int idx = blockIdx.x * 256 + threadIdx.x;
    if (idx >= total) return;
    const int Din = 1 << din_shift;
    const int i = idx & (Din - 1);
    const int o = idx >> din_shift;
    const size_t K = (size_t)9 << din_shift;
    const size_t cidx = (size_t)i * dout + o;
    float base  = sb[cidx];
    float scale = sp[cidx];
    const float* cp = coef + cidx * 8;
    _Float16* dst = WT + (size_t)o * K + i;
    dst[0] = (_Float16)base;
#pragma unroll
    for (int g = 0; g < 8; ++g) dst[(size_t)(g + 1) * Din] = (_Float16)(cp[g] * scale);
}

// ---------------------------------------------------------------------------
// GEMM 128x128 tile, BK=64, 4 waves (2x2), 4x4 16x16x32 f16 MFMA frags/wave.
// T2 XOR swizzle: LDS linear dest (global_load_lds), pre-swizzled GLOBAL
// source col-group (c8 ^= row&7), same XOR on ds_read addresses.
// Split-K over blockIdx.z, f32 atomic-add epilogue (C pre-zeroed).
// ---------------------------------------------------------------------------
DEVFN void gload16(const void* g, void* l) {
    __builtin_amdgcn_global_load_lds(
        (const __attribute__((address_space(1))) void*)g,
        (__attribute__((address_space(3))) void*)l, 16, 0, 0);
}

__global__ __launch_bounds__(256) void gemm128_f16_bt(
    const _Float16* __restrict__ A,
    const _Float16* __restrict__ WT,
    float* __restrict__ C,
    int K, int N, int klen) {
    constexpr int BK = 64;
    __shared__ _Float16 Alds[128 * BK];
    __shared__ _Float16 Blds[128 * BK];

    const int tid  = threadIdx.x;
    const int lane = tid & 63;
    const int w    = tid >> 6;
    const int wm   = w >> 1;
    const int wn   = w & 1;
    const size_t bm = (size_t)blockIdx.y * 128;
    const size_t bn = (size_t)blockIdx.x * 128;
    const int kbase = blockIdx.z * klen;

    const f32x4 vzero = {0.0f, 0.0f, 0.0f, 0.0f};
    f32x4 acc[4][4];
#pragma unroll
    for (int m = 0; m < 4; ++m)
#pragma unroll
        for (int n = 0; n < 4; ++n) acc[m][n] = vzero;

    const int srow = tid >> 3;
    const int c8   = tid & 7;

    for (int k0 = kbase; k0 < kbase + klen; k0 += BK) {
#pragma unroll
        for (int is = 0; is < 4; ++is) {
            const int r  = is * 32 + srow;
            const int sg = (c8 ^ (r & 7)) << 3;  // swizzled source col (elems)
            gload16(A + (bm + r) * (size_t)K + k0 + sg,
                    Alds + is * 2048 + w * 512);
            gload16(WT + (bn + r) * (size_t)K + k0 + sg,
                    Blds + is * 2048 + w * 512);
        }
        __syncthreads();

#pragma unroll
        for (int ks = 0; ks < BK; ks += 32) {
            f16x8 af[4], bf[4];
            const int g = (ks >> 3) + (lane >> 4);      // k col-group 0..7
#pragma unroll
            for (int m = 0; m < 4; ++m) {
                const int row = wm * 64 + m * 16 + (lane & 15);
                af[m] = *(const f16x8*)(Alds + row * BK + ((g ^ (row & 7)) << 3));
            }
#pragma unroll
            for (int n = 0; n < 4; ++n) {
                const int row = wn * 64 + n * 16 + (lane & 15);
                bf[n] = *(const f16x8*)(Blds + row * BK + ((g ^ (row & 7)) << 3));
            }
#pragma unroll
            for (int m = 0; m < 4; ++m)
#pragma unroll
                for (int n = 0; n < 4; ++n)
                    acc[m][n] = __builtin_amdgcn_mfma_f32_16x16x32_f16(
                        af[m], bf[n], acc[m][n], 0, 0, 0);
        }
        __syncthreads();
    }

    // epilogue: C/D layout col = lane&15, row = (lane>>4)*4 + reg  [m89]
    const int r0 = wm * 64 + (lane >> 4) * 4;
    const int c0 = wn * 64 + (lane & 15);
#pragma unroll
    for (int m = 0; m < 4; ++m)
#pragma unroll
        for (int n = 0; n < 4; ++n)
#pragma unroll
            for (int r = 0; r < 4; ++r)
                unsafeAtomicAdd(&C[(bm + r0 + m * 16 + r) * (size_t)N + bn + c0 + n * 16],
                                acc[m][n][r]);
}

// ---------------------------------------------------------------------------
// launch
// ---------------------------------------------------------------------------
extern "C" void kernel_launch(void* const* d_in, const int* in_sizes, int n_in,
                              void* d_out, int out_size, void* d_ws, size_t ws_size,
                              hipStream_t stream) {
    const float* x     = (const float*)d_in[0];
    const float* coef1 = (const float*)d_in[1];
    const float* sb1   = (const float*)d_in[2];
    const float* sp1   = (const float*)d_in[3];
    const float* coef2 = (const float*)d_in[4];
    const float* sb2   = (const float*)d_in[5];
    const float* sp2   = (const float*)d_in[6];
    float* out = (float*)d_out;

    const int M  = 4096;           // bsz*seq
    const int D1 = 512;            // d_model
    const int D2 = 1024;           // hidden
    const int K1 = 9 * D1;         // 4608
    const int K2 = 9 * D2;         // 9216

    char* ws = (char*)d_ws;
    float*    h    = (float*)ws;                                     // 16.78 MB
    _Float16* Aaug = (_Float16*)(ws + (size_t)M * D2 * 4);           // up to 75.5 MB
    _Float16* WT   = (_Float16*)(ws + (size_t)M * D2 * 4 + (size_t)M * K2 * 2); // 9.44 MB

    hipMemsetAsync(h, 0, (size_t)M * D2 * 4, stream);
    hipMemsetAsync(out, 0, (size_t)M * D1 * 4, stream);

    // ---- layer 1 ----
    prep_w_kernel<<<(D1 * D2) / 256, 256, 0, stream>>>(coef1, sb1, sp1, WT,
                                                       D1 * D2, 9, D2);
    prep_a_kernel<<<(M * D1) / 256, 256, 0, stream>>>(x, Aaug, M * D1, 9);
    {
        dim3 grid(D2 / 128, M / 128, 2);   // split-K x2 -> 512 blocks
        gemm128_f16_bt<<<grid, 256, 0, stream>>>(Aaug, WT, h, K1, D2, K1 / 2);
    }
    // ---- layer 2 ----
    prep_w_kernel<<<(D2 * D1) / 256, 256, 0, stream>>>(coef2, sb2, sp2, WT,
                                                       D1 * D2, 10, D1);
    prep_a_kernel<<<(M * D2) / 256, 256, 0, stream>>>(h, Aaug, M * D2, 10);
    {
        dim3 grid(D1 / 128, M / 128, 4);   // split-K x4 -> 512 blocks
        gemm128_f16_bt<<<grid, 256, 0, stream>>>(Aaug, WT, out, K2, D1, K2 / 4);
    }
}